// Round 1
// baseline (309.450 us; speedup 1.0000x reference)
//
#include <hip/hip_runtime.h>
#include <stdint.h>

typedef __attribute__((ext_vector_type(8))) short short8;
typedef __attribute__((ext_vector_type(4))) float f32x4;

__device__ __forceinline__ unsigned short f2bf(float f) {
  unsigned u = __float_as_uint(f);
  u += 0x7FFF + ((u >> 16) & 1);
  return (unsigned short)(u >> 16);
}
__device__ __forceinline__ float bf2f(unsigned short h) {
  return __uint_as_float(((unsigned)h) << 16);
}

// ---------------- f32 -> bf16 convert (x4 vectorized) ----------------
__global__ __launch_bounds__(256) void k_cvt(const float* __restrict__ in,
                                             unsigned short* __restrict__ out, int n4) {
  int i = blockIdx.x * 256 + threadIdx.x;
  if (i >= n4) return;
  float4 v = ((const float4*)in)[i];
  ushort4 o;
  o.x = f2bf(v.x); o.y = f2bf(v.y); o.z = f2bf(v.z); o.w = f2bf(v.w);
  ((ushort4*)out)[i] = o;
}

// ---------------- zero the seq-pad columns of Vt ----------------
__global__ __launch_bounds__(256) void k_zpad(unsigned short* __restrict__ vt) {
  const int TOT = 768 * 64 * 27;  // (B*H)*(Hd)*(224-197)
  int i = blockIdx.x * 256 + threadIdx.x;
  if (i >= TOT) return;
  int row = i / 27, c = i - row * 27;
  vt[row * 224 + 197 + c] = 0;
}

// ---------------- rank-8 LoRA low = 2 * X @ A^T  (f32 accurate) ----------------
template <int IN_BF16>
__global__ __launch_bounds__(256) void k_low(const void* __restrict__ xin,
                                             const float* __restrict__ lora_a,
                                             float* __restrict__ low, int M) {
  __shared__ float As[8 * 768];
  for (int i = threadIdx.x; i < 8 * 768; i += 256) As[i] = lora_a[i];
  __syncthreads();
  int w = threadIdx.x >> 6, l = threadIdx.x & 63;
  int m = blockIdx.x * 4 + w;
  if (m >= M) return;
  float acc[8] = {0, 0, 0, 0, 0, 0, 0, 0};
  for (int j = 0; j < 12; ++j) {
    int d = j * 64 + l;
    float xv;
    if (IN_BF16) xv = bf2f(((const unsigned short*)xin)[(size_t)m * 768 + d]);
    else         xv = ((const float*)xin)[(size_t)m * 768 + d];
#pragma unroll
    for (int r = 0; r < 8; ++r) acc[r] += xv * As[r * 768 + d];
  }
#pragma unroll
  for (int r = 0; r < 8; ++r)
    for (int dd = 1; dd < 64; dd <<= 1) acc[r] += __shfl_xor(acc[r], dd);
  if (l == 0) {
#pragma unroll
    for (int r = 0; r < 8; ++r) low[m * 8 + r] = 2.0f * acc[r];
  }
}

// ---------------- qkv GEMM: [M,768]x[2304,768]^T + bias + LoRA, scatter to Q/K/Vt ----------------
__global__ __launch_bounds__(256) void k_gemm_qkv(
    const unsigned short* __restrict__ A, const unsigned short* __restrict__ Bw,
    const float* __restrict__ bias, const float* __restrict__ low,
    const float* __restrict__ lorab, unsigned short* __restrict__ Qg,
    unsigned short* __restrict__ Kg, unsigned short* __restrict__ Vtg, int M) {
  __shared__ __align__(16) unsigned short As[128 * 32];
  __shared__ __align__(16) unsigned short Bs[128 * 32];
  const int w = threadIdx.x >> 6, l = threadIdx.x & 63;
  const int lr = l & 15, lg = l >> 4;
  const int m0 = blockIdx.y * 128, n0 = blockIdx.x * 128;
  const int wm = w >> 1, wn = w & 1;
  f32x4 acc[4][4];
#pragma unroll
  for (int i = 0; i < 4; ++i)
#pragma unroll
    for (int j = 0; j < 4; ++j) acc[i][j] = (f32x4){0.f, 0.f, 0.f, 0.f};

  auto* As3 = (__attribute__((address_space(3))) unsigned short*)As;
  auto* Bs3 = (__attribute__((address_space(3))) unsigned short*)Bs;
  const int srow = l >> 2;
  const int skof = (l & 3) * 8;
  for (int kt = 0; kt < 24; ++kt) {
    const int k0 = kt * 32;
    __syncthreads();
#pragma unroll
    for (int i = 0; i < 2; ++i) {
      int c = w * 2 + i;
      int arow = m0 + c * 16 + srow;
      arow = min(arow, M - 1);
      const unsigned short* ga = A + (size_t)arow * 768 + k0 + skof;
      __builtin_amdgcn_global_load_lds((const __attribute__((address_space(1))) void*)ga,
                                       (__attribute__((address_space(3))) void*)(As3 + c * 512),
                                       16, 0, 0);
      int brow = n0 + c * 16 + srow;
      const unsigned short* gb = Bw + (size_t)brow * 768 + k0 + skof;
      __builtin_amdgcn_global_load_lds((const __attribute__((address_space(1))) void*)gb,
                                       (__attribute__((address_space(3))) void*)(Bs3 + c * 512),
                                       16, 0, 0);
    }
    __syncthreads();
    short8 af[4], bf[4];
#pragma unroll
    for (int i = 0; i < 4; ++i) af[i] = *(const short8*)(As + (wm * 64 + i * 16 + lr) * 32 + lg * 8);
#pragma unroll
    for (int j = 0; j < 4; ++j) bf[j] = *(const short8*)(Bs + (wn * 64 + j * 16 + lr) * 32 + lg * 8);
#pragma unroll
    for (int i = 0; i < 4; ++i)
#pragma unroll
      for (int j = 0; j < 4; ++j)
        acc[i][j] = __builtin_amdgcn_mfma_f32_16x16x32_bf16(af[i], bf[j], acc[i][j], 0, 0, 0);
  }
#pragma unroll
  for (int j = 0; j < 4; ++j) {
    int o = n0 + wn * 64 + j * 16 + lr;
    float bo = bias[o];
    float lb[8];
#pragma unroll
    for (int r = 0; r < 8; ++r) lb[r] = lorab[o * 8 + r];
    int which = o / 768;
    int within = o - which * 768;
    int hh = within >> 6, hd = within & 63;
#pragma unroll
    for (int i = 0; i < 4; ++i) {
#pragma unroll
      for (int v = 0; v < 4; ++v) {
        int m = m0 + wm * 64 + i * 16 + lg * 4 + v;
        if (m < M) {
          float val = acc[i][j][v] + bo;
          const float* lp = low + m * 8;
#pragma unroll
          for (int r = 0; r < 8; ++r) val += lp[r] * lb[r];
          int b = m / 197;
          int n = m - b * 197;
          int bh = b * 12 + hh;
          unsigned short hv = f2bf(val);
          if (which == 0)      Qg[(bh * 224 + n) * 64 + hd] = hv;
          else if (which == 1) Kg[(bh * 224 + n) * 64 + hd] = hv;
          else                 Vtg[(bh * 64 + hd) * 224 + n] = hv;
        }
      }
    }
  }
}

// ---------------- attention: one block per (b,h), full-row softmax ----------------
__global__ __launch_bounds__(256) void k_attn(const unsigned short* __restrict__ Qg,
                                              const unsigned short* __restrict__ Kg,
                                              const unsigned short* __restrict__ Vtg,
                                              unsigned short* __restrict__ aout) {
  __shared__ __align__(16) unsigned short Ps[4][16 * 224];
  const int bh = blockIdx.x;
  const int b = bh / 12, h = bh - b * 12;
  const unsigned short* Qb = Qg + (size_t)bh * (224 * 64);
  const unsigned short* Kb = Kg + (size_t)bh * (224 * 64);
  const unsigned short* Vb = Vtg + (size_t)bh * (64 * 224);
  const int w = threadIdx.x >> 6, l = threadIdx.x & 63;
  const int lr = l & 15, lg = l >> 4;
  for (int t = w; t < 13; t += 4) {
    const int q0 = t * 16;
    short8 aq0 = *(const short8*)(Qb + (q0 + lr) * 64 + lg * 8);
    short8 aq1 = *(const short8*)(Qb + (q0 + lr) * 64 + 32 + lg * 8);
    f32x4 s[14];
#pragma unroll
    for (int jt = 0; jt < 14; ++jt) {
      f32x4 a = (f32x4){0.f, 0.f, 0.f, 0.f};
      short8 bk0 = *(const short8*)(Kb + (jt * 16 + lr) * 64 + lg * 8);
      short8 bk1 = *(const short8*)(Kb + (jt * 16 + lr) * 64 + 32 + lg * 8);
      a = __builtin_amdgcn_mfma_f32_16x16x32_bf16(aq0, bk0, a, 0, 0, 0);
      a = __builtin_amdgcn_mfma_f32_16x16x32_bf16(aq1, bk1, a, 0, 0, 0);
      s[jt] = a;
    }
    float mx[4] = {-3.0e38f, -3.0e38f, -3.0e38f, -3.0e38f};
#pragma unroll
    for (int jt = 0; jt < 14; ++jt) {
      bool valid = (jt * 16 + lr) < 197;
#pragma unroll
      for (int v = 0; v < 4; ++v) {
        float sv = valid ? s[jt][v] : -1.0e30f;
        s[jt][v] = sv;
        mx[v] = fmaxf(mx[v], sv);
      }
    }
#pragma unroll
    for (int v = 0; v < 4; ++v) {
      mx[v] = fmaxf(mx[v], __shfl_xor(mx[v], 1));
      mx[v] = fmaxf(mx[v], __shfl_xor(mx[v], 2));
      mx[v] = fmaxf(mx[v], __shfl_xor(mx[v], 4));
      mx[v] = fmaxf(mx[v], __shfl_xor(mx[v], 8));
    }
    float sum[4] = {0.f, 0.f, 0.f, 0.f};
    const float cc = 0.125f * 1.44269504088896341f;
#pragma unroll
    for (int jt = 0; jt < 14; ++jt)
#pragma unroll
      for (int v = 0; v < 4; ++v) {
        float pv = exp2f((s[jt][v] - mx[v]) * cc);
        s[jt][v] = pv;
        sum[v] += pv;
      }
#pragma unroll
    for (int v = 0; v < 4; ++v) {
      sum[v] += __shfl_xor(sum[v], 1);
      sum[v] += __shfl_xor(sum[v], 2);
      sum[v] += __shfl_xor(sum[v], 4);
      sum[v] += __shfl_xor(sum[v], 8);
    }
    float inv[4];
#pragma unroll
    for (int v = 0; v < 4; ++v) inv[v] = 1.0f / sum[v];
    unsigned short* pw = &Ps[w][0];
#pragma unroll
    for (int jt = 0; jt < 14; ++jt)
#pragma unroll
      for (int v = 0; v < 4; ++v)
        pw[(lg * 4 + v) * 224 + jt * 16 + lr] = f2bf(s[jt][v] * inv[v]);
    f32x4 oacc[4];
#pragma unroll
    for (int jo = 0; jo < 4; ++jo) oacc[jo] = (f32x4){0.f, 0.f, 0.f, 0.f};
#pragma unroll
    for (int kk = 0; kk < 7; ++kk) {
      short8 pa = *(const short8*)(pw + lr * 224 + kk * 32 + lg * 8);
#pragma unroll
      for (int jo = 0; jo < 4; ++jo) {
        short8 bv = *(const short8*)(Vb + (jo * 16 + lr) * 224 + kk * 32 + lg * 8);
        oacc[jo] = __builtin_amdgcn_mfma_f32_16x16x32_bf16(pa, bv, oacc[jo], 0, 0, 0);
      }
    }
#pragma unroll
    for (int jo = 0; jo < 4; ++jo)
#pragma unroll
      for (int v = 0; v < 4; ++v) {
        int n = q0 + lg * 4 + v;
        if (n < 197) aout[((size_t)(b * 197 + n)) * 768 + h * 64 + jo * 16 + lr] = f2bf(oacc[jo][v]);
      }
  }
}

// ---------------- out GEMM: [M,768]x[768,768]^T + bias + LoRA -> f32 out ----------------
__global__ __launch_bounds__(256) void k_gemm_out(
    const unsigned short* __restrict__ A, const unsigned short* __restrict__ Bw,
    const float* __restrict__ bias, const float* __restrict__ low,
    const float* __restrict__ lorab, float* __restrict__ out, int M) {
  __shared__ __align__(16) unsigned short As[128 * 32];
  __shared__ __align__(16) unsigned short Bs[128 * 32];
  const int w = threadIdx.x >> 6, l = threadIdx.x & 63;
  const int lr = l & 15, lg = l >> 4;
  const int m0 = blockIdx.y * 128, n0 = blockIdx.x * 128;
  const int wm = w >> 1, wn = w & 1;
  f32x4 acc[4][4];
#pragma unroll
  for (int i = 0; i < 4; ++i)
#pragma unroll
    for (int j = 0; j < 4; ++j) acc[i][j] = (f32x4){0.f, 0.f, 0.f, 0.f};

  auto* As3 = (__attribute__((address_space(3))) unsigned short*)As;
  auto* Bs3 = (__attribute__((address_space(3))) unsigned short*)Bs;
  const int srow = l >> 2;
  const int skof = (l & 3) * 8;
  for (int kt = 0; kt < 24; ++kt) {
    const int k0 = kt * 32;
    __syncthreads();
#pragma unroll
    for (int i = 0; i < 2; ++i) {
      int c = w * 2 + i;
      int arow = m0 + c * 16 + srow;
      arow = min(arow, M - 1);
      const unsigned short* ga = A + (size_t)arow * 768 + k0 + skof;
      __builtin_amdgcn_global_load_lds((const __attribute__((address_space(1))) void*)ga,
                                       (__attribute__((address_space(3))) void*)(As3 + c * 512),
                                       16, 0, 0);
      int brow = n0 + c * 16 + srow;
      const unsigned short* gb = Bw + (size_t)brow * 768 + k0 + skof;
      __builtin_amdgcn_global_load_lds((const __attribute__((address_space(1))) void*)gb,
                                       (__attribute__((address_space(3))) void*)(Bs3 + c * 512),
                                       16, 0, 0);
    }
    __syncthreads();
    short8 af[4], bf[4];
#pragma unroll
    for (int i = 0; i < 4; ++i) af[i] = *(const short8*)(As + (wm * 64 + i * 16 + lr) * 32 + lg * 8);
#pragma unroll
    for (int j = 0; j < 4; ++j) bf[j] = *(const short8*)(Bs + (wn * 64 + j * 16 + lr) * 32 + lg * 8);
#pragma unroll
    for (int i = 0; i < 4; ++i)
#pragma unroll
      for (int j = 0; j < 4; ++j)
        acc[i][j] = __builtin_amdgcn_mfma_f32_16x16x32_bf16(af[i], bf[j], acc[i][j], 0, 0, 0);
  }
#pragma unroll
  for (int j = 0; j < 4; ++j) {
    int o = n0 + wn * 64 + j * 16 + lr;
    float bo = bias[o];
    float lb[8];
#pragma unroll
    for (int r = 0; r < 8; ++r) lb[r] = lorab[o * 8 + r];
#pragma unroll
    for (int i = 0; i < 4; ++i) {
#pragma unroll
      for (int v = 0; v < 4; ++v) {
        int m = m0 + wm * 64 + i * 16 + lg * 4 + v;
        if (m < M) {
          float val = acc[i][j][v] + bo;
          const float* lp = low + m * 8;
#pragma unroll
          for (int r = 0; r < 8; ++r) val += lp[r] * lb[r];
          out[(size_t)m * 768 + o] = val;
        }
      }
    }
  }
}

extern "C" void kernel_launch(void* const* d_in, const int* in_sizes, int n_in,
                              void* d_out, int out_size, void* d_ws, size_t ws_size,
                              hipStream_t stream) {
  const float* x      = (const float*)d_in[0];
  const float* qkv_w  = (const float*)d_in[1];
  const float* qkv_b  = (const float*)d_in[2];
  const float* qkv_la = (const float*)d_in[3];
  const float* qkv_lb = (const float*)d_in[4];
  const float* out_w  = (const float*)d_in[5];
  const float* out_b  = (const float*)d_in[6];
  const float* out_la = (const float*)d_in[7];
  const float* out_lb = (const float*)d_in[8];
  float* out = (float*)d_out;

  const int M = 64 * 197;  // 12608
  char* p = (char*)d_ws;
  auto carve = [&](size_t bytes) {
    char* r = p;
    p += (bytes + 255) & ~(size_t)255;
    return r;
  };
  unsigned short* xbf  = (unsigned short*)carve((size_t)M * 768 * 2);
  unsigned short* qwbf = (unsigned short*)carve((size_t)2304 * 768 * 2);
  unsigned short* owbf = (unsigned short*)carve((size_t)768 * 768 * 2);
  float* lowq          = (float*)carve((size_t)M * 8 * 4);
  float* lowo          = (float*)carve((size_t)M * 8 * 4);
  unsigned short* Qg   = (unsigned short*)carve((size_t)768 * 224 * 64 * 2);
  unsigned short* Kg   = (unsigned short*)carve((size_t)768 * 224 * 64 * 2);
  unsigned short* Vtg  = (unsigned short*)carve((size_t)768 * 64 * 224 * 2);
  unsigned short* aout = xbf;  // reuse: x_bf16 dead after qkv GEMM

  int n4x = M * 768 / 4, n4q = 2304 * 768 / 4, n4o = 768 * 768 / 4;
  k_cvt<<<(n4x + 255) / 256, 256, 0, stream>>>(x, xbf, n4x);
  k_cvt<<<(n4q + 255) / 256, 256, 0, stream>>>(qkv_w, qwbf, n4q);
  k_cvt<<<(n4o + 255) / 256, 256, 0, stream>>>(out_w, owbf, n4o);
  k_zpad<<<(768 * 64 * 27 + 255) / 256, 256, 0, stream>>>(Vtg);
  k_low<0><<<(M + 3) / 4, 256, 0, stream>>>((const void*)x, qkv_la, lowq, M);
  k_gemm_qkv<<<dim3(18, 99), 256, 0, stream>>>(xbf, qwbf, qkv_b, lowq, qkv_lb, Qg, Kg, Vtg, M);
  k_attn<<<768, 256, 0, stream>>>(Qg, Kg, Vtg, aout);
  k_low<1><<<(M + 3) / 4, 256, 0, stream>>>((const void*)aout, out_la, lowo, M);
  k_gemm_out<<<dim3(6, 99), 256, 0, stream>>>(aout, owbf, out_b, lowo, out_lb, out, M);
}

// Round 2
// 302.234 us; speedup vs baseline: 1.0239x; 1.0239x over previous
//
#include <hip/hip_runtime.h>
#include <stdint.h>

typedef __attribute__((ext_vector_type(8))) short short8;
typedef __attribute__((ext_vector_type(4))) float f32x4;

__device__ __forceinline__ unsigned short f2bf(float f) {
  unsigned u = __float_as_uint(f);
  u += 0x7FFF + ((u >> 16) & 1);
  return (unsigned short)(u >> 16);
}
__device__ __forceinline__ float bf2f(unsigned short h) {
  return __uint_as_float(((unsigned)h) << 16);
}

// ---------------- f32 -> bf16 convert (x4 vectorized) ----------------
__global__ __launch_bounds__(256) void k_cvt(const float* __restrict__ in,
                                             unsigned short* __restrict__ out, int n4) {
  int i = blockIdx.x * 256 + threadIdx.x;
  if (i >= n4) return;
  float4 v = ((const float4*)in)[i];
  ushort4 o;
  o.x = f2bf(v.x); o.y = f2bf(v.y); o.z = f2bf(v.z); o.w = f2bf(v.w);
  ((ushort4*)out)[i] = o;
}

// ---------------- zero the seq-pad columns of Vt ----------------
__global__ __launch_bounds__(256) void k_zpad(unsigned short* __restrict__ vt) {
  const int TOT = 768 * 64 * 27;  // (B*H)*(Hd)*(224-197)
  int i = blockIdx.x * 256 + threadIdx.x;
  if (i >= TOT) return;
  int row = i / 27, c = i - row * 27;
  vt[row * 224 + 197 + c] = 0;
}

// ---------------- rank-8 LoRA low = 2 * X @ A^T  (f32 accumulate, bf16 x) ----------------
__global__ __launch_bounds__(256) void k_low(const unsigned short* __restrict__ xin,
                                             const float* __restrict__ lora_a,
                                             float* __restrict__ low, int M) {
  __shared__ float As[8 * 768];
  for (int i = threadIdx.x; i < 8 * 768; i += 256) As[i] = lora_a[i];
  __syncthreads();
  int w = threadIdx.x >> 6, l = threadIdx.x & 63;
  int m = blockIdx.x * 4 + w;
  if (m >= M) return;
  float acc[8] = {0, 0, 0, 0, 0, 0, 0, 0};
  for (int j = 0; j < 12; ++j) {
    int d = j * 64 + l;
    float xv = bf2f(xin[(size_t)m * 768 + d]);
#pragma unroll
    for (int r = 0; r < 8; ++r) acc[r] += xv * As[r * 768 + d];
  }
#pragma unroll
  for (int r = 0; r < 8; ++r)
    for (int dd = 1; dd < 64; dd <<= 1) acc[r] += __shfl_xor(acc[r], dd);
  if (l == 0) {
#pragma unroll
    for (int r = 0; r < 8; ++r) low[m * 8 + r] = 2.0f * acc[r];
  }
}

// ---------------- pipelined GEMM (depth-2, 3 LDS buffers, counted vmcnt) ----------------
// MODE 0: qkv  [M,768]x[2304,768]^T + bias + LoRA -> scatter Q/K/Vt (bf16)
// MODE 1: out  [M,768]x[768,768]^T  + bias + LoRA -> f32 out
template <int MODE>
__global__ __launch_bounds__(256) void k_gemm2(
    const unsigned short* __restrict__ A, const unsigned short* __restrict__ Bw,
    const float* __restrict__ bias, const float* __restrict__ low,
    const float* __restrict__ lorab, unsigned short* __restrict__ Qg,
    unsigned short* __restrict__ Kg, unsigned short* __restrict__ Vtg,
    float* __restrict__ outp, int M, int nbx) {
  __shared__ __align__(16) unsigned short As[3][128 * 32];
  __shared__ __align__(16) unsigned short Bs[3][128 * 32];
  const int w = threadIdx.x >> 6, l = threadIdx.x & 63;
  const int lr = l & 15, lg = l >> 4;
  // bijective XCD-aware swizzle (m204): consecutive wgid chunks per XCD,
  // N-tile fastest so a chunk reuses one A-panel + B from its own L2.
  const int nwg = gridDim.x;
  const int orig = blockIdx.x;
  const int qq = nwg >> 3, rr = nwg & 7, xcd = orig & 7;
  const int wgid = (xcd < rr ? xcd * (qq + 1) : rr * (qq + 1) + (xcd - rr) * qq) + (orig >> 3);
  const int bx = wgid % nbx, by = wgid / nbx;
  const int m0 = by * 128, n0 = bx * 128;
  const int wm = w >> 1, wn = w & 1;
  f32x4 acc[4][4];
#pragma unroll
  for (int i = 0; i < 4; ++i)
#pragma unroll
    for (int j = 0; j < 4; ++j) acc[i][j] = (f32x4){0.f, 0.f, 0.f, 0.f};

  auto* As3 = (__attribute__((address_space(3))) unsigned short*)&As[0][0];
  auto* Bs3 = (__attribute__((address_space(3))) unsigned short*)&Bs[0][0];
  const int srow = l >> 2;
  const int skof = (l & 3) * 8;

  auto STAGE = [&](int buf, int kt) {
    const int k0 = kt * 32;
#pragma unroll
    for (int i = 0; i < 2; ++i) {
      int c = w * 2 + i;
      int arow = min(m0 + c * 16 + srow, M - 1);
      const unsigned short* ga = A + (size_t)arow * 768 + k0 + skof;
      __builtin_amdgcn_global_load_lds((const __attribute__((address_space(1))) void*)ga,
                                       (__attribute__((address_space(3))) void*)(As3 + buf * 4096 + c * 512),
                                       16, 0, 0);
      int brow = n0 + c * 16 + srow;
      const unsigned short* gb = Bw + (size_t)brow * 768 + k0 + skof;
      __builtin_amdgcn_global_load_lds((const __attribute__((address_space(1))) void*)gb,
                                       (__attribute__((address_space(3))) void*)(Bs3 + buf * 4096 + c * 512),
                                       16, 0, 0);
    }
  };

  // prologue: stage tiles 0,1; wait tile0 (4 loads of tile1 still in flight)
  STAGE(0, 0);
  STAGE(1, 1);
  asm volatile("s_waitcnt vmcnt(4)" ::: "memory");
  __builtin_amdgcn_sched_barrier(0);
  __builtin_amdgcn_s_barrier();

  for (int kt = 0; kt < 24; ++kt) {
    const int cur = kt - (kt / 3) * 3;  // kt % 3
    if (kt + 2 < 24) STAGE((kt + 2) % 3, kt + 2);
    const unsigned short* Ab = &As[cur][0];
    const unsigned short* Bb = &Bs[cur][0];
    short8 af[4], bfr[4];
#pragma unroll
    for (int i = 0; i < 4; ++i) af[i] = *(const short8*)(Ab + (wm * 64 + i * 16 + lr) * 32 + lg * 8);
#pragma unroll
    for (int j = 0; j < 4; ++j) bfr[j] = *(const short8*)(Bb + (wn * 64 + j * 16 + lr) * 32 + lg * 8);
#pragma unroll
    for (int i = 0; i < 4; ++i)
#pragma unroll
      for (int j = 0; j < 4; ++j)
        acc[i][j] = __builtin_amdgcn_mfma_f32_16x16x32_bf16(af[i], bfr[j], acc[i][j], 0, 0, 0);
    if (kt + 1 < 24) {
      if (kt + 2 < 24) {
        asm volatile("s_waitcnt vmcnt(4)" ::: "memory");  // next tile landed; deepest stays in flight
      } else {
        asm volatile("s_waitcnt vmcnt(0)" ::: "memory");  // drain for last tile
      }
      __builtin_amdgcn_sched_barrier(0);
      __builtin_amdgcn_s_barrier();
    }
  }

  // epilogue
#pragma unroll
  for (int j = 0; j < 4; ++j) {
    int o = n0 + wn * 64 + j * 16 + lr;
    float bo = bias[o];
    const float4* lb4 = (const float4*)(lorab + (size_t)o * 8);
    float4 lb0 = lb4[0], lb1 = lb4[1];
    int which = 0, hh = 0, hd = 0;
    if (MODE == 0) {
      which = o / 768;
      int within = o - which * 768;
      hh = within >> 6;
      hd = within & 63;
    }
#pragma unroll
    for (int i = 0; i < 4; ++i) {
#pragma unroll
      for (int v = 0; v < 4; ++v) {
        int m = m0 + wm * 64 + i * 16 + lg * 4 + v;
        if (m < M) {
          const float4* lp4 = (const float4*)(low + (size_t)m * 8);
          float4 l0 = lp4[0], l1 = lp4[1];
          float val = acc[i][j][v] + bo;
          val += l0.x * lb0.x + l0.y * lb0.y + l0.z * lb0.z + l0.w * lb0.w;
          val += l1.x * lb1.x + l1.y * lb1.y + l1.z * lb1.z + l1.w * lb1.w;
          if (MODE == 0) {
            int b = m / 197;
            int n = m - b * 197;
            int bh = b * 12 + hh;
            unsigned short hv = f2bf(val);
            if (which == 0)      Qg[(bh * 224 + n) * 64 + hd] = hv;
            else if (which == 1) Kg[(bh * 224 + n) * 64 + hd] = hv;
            else                 Vtg[(bh * 64 + hd) * 224 + n] = hv;
          } else {
            outp[(size_t)m * 768 + o] = val;
          }
        }
      }
    }
  }
}

// ---------------- attention: one block per (b,h), full-row softmax ----------------
__global__ __launch_bounds__(256) void k_attn(const unsigned short* __restrict__ Qg,
                                              const unsigned short* __restrict__ Kg,
                                              const unsigned short* __restrict__ Vtg,
                                              unsigned short* __restrict__ aout) {
  __shared__ __align__(16) unsigned short Ps[4][16 * 224];
  const int bh = blockIdx.x;
  const int b = bh / 12, h = bh - b * 12;
  const unsigned short* Qb = Qg + (size_t)bh * (224 * 64);
  const unsigned short* Kb = Kg + (size_t)bh * (224 * 64);
  const unsigned short* Vb = Vtg + (size_t)bh * (64 * 224);
  const int w = threadIdx.x >> 6, l = threadIdx.x & 63;
  const int lr = l & 15, lg = l >> 4;
  for (int t = w; t < 13; t += 4) {
    const int q0 = t * 16;
    short8 aq0 = *(const short8*)(Qb + (q0 + lr) * 64 + lg * 8);
    short8 aq1 = *(const short8*)(Qb + (q0 + lr) * 64 + 32 + lg * 8);
    f32x4 s[14];
#pragma unroll
    for (int jt = 0; jt < 14; ++jt) {
      f32x4 a = (f32x4){0.f, 0.f, 0.f, 0.f};
      short8 bk0 = *(const short8*)(Kb + (jt * 16 + lr) * 64 + lg * 8);
      short8 bk1 = *(const short8*)(Kb + (jt * 16 + lr) * 64 + 32 + lg * 8);
      a = __builtin_amdgcn_mfma_f32_16x16x32_bf16(aq0, bk0, a, 0, 0, 0);
      a = __builtin_amdgcn_mfma_f32_16x16x32_bf16(aq1, bk1, a, 0, 0, 0);
      s[jt] = a;
    }
    float mx[4] = {-3.0e38f, -3.0e38f, -3.0e38f, -3.0e38f};
#pragma unroll
    for (int jt = 0; jt < 14; ++jt) {
      bool valid = (jt * 16 + lr) < 197;
#pragma unroll
      for (int v = 0; v < 4; ++v) {
        float sv = valid ? s[jt][v] : -1.0e30f;
        s[jt][v] = sv;
        mx[v] = fmaxf(mx[v], sv);
      }
    }
#pragma unroll
    for (int v = 0; v < 4; ++v) {
      mx[v] = fmaxf(mx[v], __shfl_xor(mx[v], 1));
      mx[v] = fmaxf(mx[v], __shfl_xor(mx[v], 2));
      mx[v] = fmaxf(mx[v], __shfl_xor(mx[v], 4));
      mx[v] = fmaxf(mx[v], __shfl_xor(mx[v], 8));
    }
    float sum[4] = {0.f, 0.f, 0.f, 0.f};
    const float cc = 0.125f * 1.44269504088896341f;
#pragma unroll
    for (int jt = 0; jt < 14; ++jt)
#pragma unroll
      for (int v = 0; v < 4; ++v) {
        float pv = exp2f((s[jt][v] - mx[v]) * cc);
        s[jt][v] = pv;
        sum[v] += pv;
      }
#pragma unroll
    for (int v = 0; v < 4; ++v) {
      sum[v] += __shfl_xor(sum[v], 1);
      sum[v] += __shfl_xor(sum[v], 2);
      sum[v] += __shfl_xor(sum[v], 4);
      sum[v] += __shfl_xor(sum[v], 8);
    }
    float inv[4];
#pragma unroll
    for (int v = 0; v < 4; ++v) inv[v] = 1.0f / sum[v];
    unsigned short* pw = &Ps[w][0];
#pragma unroll
    for (int jt = 0; jt < 14; ++jt)
#pragma unroll
      for (int v = 0; v < 4; ++v)
        pw[(lg * 4 + v) * 224 + jt * 16 + lr] = f2bf(s[jt][v] * inv[v]);
    f32x4 oacc[4];
#pragma unroll
    for (int jo = 0; jo < 4; ++jo) oacc[jo] = (f32x4){0.f, 0.f, 0.f, 0.f};
#pragma unroll
    for (int kk = 0; kk < 7; ++kk) {
      short8 pa = *(const short8*)(pw + lr * 224 + kk * 32 + lg * 8);
#pragma unroll
      for (int jo = 0; jo < 4; ++jo) {
        short8 bv = *(const short8*)(Vb + (jo * 16 + lr) * 224 + kk * 32 + lg * 8);
        oacc[jo] = __builtin_amdgcn_mfma_f32_16x16x32_bf16(pa, bv, oacc[jo], 0, 0, 0);
      }
    }
#pragma unroll
    for (int jo = 0; jo < 4; ++jo)
#pragma unroll
      for (int v = 0; v < 4; ++v) {
        int n = q0 + lg * 4 + v;
        if (n < 197) aout[((size_t)(b * 197 + n)) * 768 + h * 64 + jo * 16 + lr] = f2bf(oacc[jo][v]);
      }
  }
}

extern "C" void kernel_launch(void* const* d_in, const int* in_sizes, int n_in,
                              void* d_out, int out_size, void* d_ws, size_t ws_size,
                              hipStream_t stream) {
  const float* x      = (const float*)d_in[0];
  const float* qkv_w  = (const float*)d_in[1];
  const float* qkv_b  = (const float*)d_in[2];
  const float* qkv_la = (const float*)d_in[3];
  const float* qkv_lb = (const float*)d_in[4];
  const float* out_w  = (const float*)d_in[5];
  const float* out_b  = (const float*)d_in[6];
  const float* out_la = (const float*)d_in[7];
  const float* out_lb = (const float*)d_in[8];
  float* out = (float*)d_out;

  const int M = 64 * 197;  // 12608
  char* p = (char*)d_ws;
  auto carve = [&](size_t bytes) {
    char* r = p;
    p += (bytes + 255) & ~(size_t)255;
    return r;
  };
  unsigned short* xbf  = (unsigned short*)carve((size_t)M * 768 * 2);
  unsigned short* qwbf = (unsigned short*)carve((size_t)2304 * 768 * 2);
  unsigned short* owbf = (unsigned short*)carve((size_t)768 * 768 * 2);
  float* lowq          = (float*)carve((size_t)M * 8 * 4);
  float* lowo          = (float*)carve((size_t)M * 8 * 4);
  unsigned short* Qg   = (unsigned short*)carve((size_t)768 * 224 * 64 * 2);
  unsigned short* Kg   = (unsigned short*)carve((size_t)768 * 224 * 64 * 2);
  unsigned short* Vtg  = (unsigned short*)carve((size_t)768 * 64 * 224 * 2);
  unsigned short* aout = xbf;  // reuse: x_bf16 dead after qkv GEMM

  int n4x = M * 768 / 4, n4q = 2304 * 768 / 4, n4o = 768 * 768 / 4;
  k_cvt<<<(n4x + 255) / 256, 256, 0, stream>>>(x, xbf, n4x);
  k_cvt<<<(n4q + 255) / 256, 256, 0, stream>>>(qkv_w, qwbf, n4q);
  k_cvt<<<(n4o + 255) / 256, 256, 0, stream>>>(out_w, owbf, n4o);
  k_zpad<<<(768 * 64 * 27 + 255) / 256, 256, 0, stream>>>(Vtg);
  k_low<<<(M + 3) / 4, 256, 0, stream>>>(xbf, qkv_la, lowq, M);
  k_gemm2<0><<<18 * 99, 256, 0, stream>>>(xbf, qwbf, qkv_b, lowq, qkv_lb, Qg, Kg, Vtg, nullptr, M, 18);
  k_attn<<<768, 256, 0, stream>>>(Qg, Kg, Vtg, aout);
  k_low<<<(M + 3) / 4, 256, 0, stream>>>(aout, out_la, lowo, M);
  k_gemm2<1><<<6 * 99, 256, 0, stream>>>(aout, owbf, out_b, lowo, out_lb, nullptr, nullptr, nullptr, out, M, 6);
}

// Round 3
// 260.358 us; speedup vs baseline: 1.1886x; 1.1608x over previous
//
#include <hip/hip_runtime.h>
#include <stdint.h>

typedef __attribute__((ext_vector_type(8))) short short8;
typedef __attribute__((ext_vector_type(4))) float f32x4;

#define SB __builtin_amdgcn_sched_barrier(0)
#define BAR __builtin_amdgcn_s_barrier()

__device__ __forceinline__ unsigned short f2bf(float f) {
  unsigned u = __float_as_uint(f);
  u += 0x7FFF + ((u >> 16) & 1);
  return (unsigned short)(u >> 16);
}
__device__ __forceinline__ float bf2f(unsigned short h) {
  return __uint_as_float(((unsigned)h) << 16);
}

// ---------------- f32 -> bf16 convert (x4 vectorized) ----------------
__global__ __launch_bounds__(256) void k_cvt(const float* __restrict__ in,
                                             unsigned short* __restrict__ out, int n4) {
  int i = blockIdx.x * 256 + threadIdx.x;
  if (i >= n4) return;
  float4 v = ((const float4*)in)[i];
  ushort4 o;
  o.x = f2bf(v.x); o.y = f2bf(v.y); o.z = f2bf(v.z); o.w = f2bf(v.w);
  ((ushort4*)out)[i] = o;
}

// ---------------- zero the seq-pad columns of Vt ----------------
__global__ __launch_bounds__(256) void k_zpad(unsigned short* __restrict__ vt) {
  const int TOT = 768 * 64 * 27;
  int i = blockIdx.x * 256 + threadIdx.x;
  if (i >= TOT) return;
  int row = i / 27, c = i - row * 27;
  vt[row * 224 + 197 + c] = 0;
}

// ---------------- fused: x f32 -> bf16 + low = 2*X@A^T ----------------
__global__ __launch_bounds__(256) void k_lowcvt(const float* __restrict__ x,
                                                const float* __restrict__ lora_a,
                                                unsigned short* __restrict__ xbf,
                                                float* __restrict__ low, int M) {
  __shared__ float As[8 * 768];
  for (int i = threadIdx.x; i < 8 * 768; i += 256) As[i] = lora_a[i];
  __syncthreads();
  int w = threadIdx.x >> 6, l = threadIdx.x & 63;
  int m = blockIdx.x * 4 + w;
  if (m >= M) return;
  float acc[8] = {0, 0, 0, 0, 0, 0, 0, 0};
  for (int j = 0; j < 12; ++j) {
    int d = j * 64 + l;
    float xv = x[(size_t)m * 768 + d];
    xbf[(size_t)m * 768 + d] = f2bf(xv);
#pragma unroll
    for (int r = 0; r < 8; ++r) acc[r] += xv * As[r * 768 + d];
  }
#pragma unroll
  for (int r = 0; r < 8; ++r)
    for (int dd = 1; dd < 64; dd <<= 1) acc[r] += __shfl_xor(acc[r], dd);
  if (l == 0) {
#pragma unroll
    for (int r = 0; r < 8; ++r) low[m * 8 + r] = 2.0f * acc[r];
  }
}

// ---------------- rank-8 LoRA low = 2 * X @ A^T  (bf16 input) ----------------
__global__ __launch_bounds__(256) void k_low(const unsigned short* __restrict__ xin,
                                             const float* __restrict__ lora_a,
                                             float* __restrict__ low, int M) {
  __shared__ float As[8 * 768];
  for (int i = threadIdx.x; i < 8 * 768; i += 256) As[i] = lora_a[i];
  __syncthreads();
  int w = threadIdx.x >> 6, l = threadIdx.x & 63;
  int m = blockIdx.x * 4 + w;
  if (m >= M) return;
  float acc[8] = {0, 0, 0, 0, 0, 0, 0, 0};
  for (int j = 0; j < 12; ++j) {
    int d = j * 64 + l;
    float xv = bf2f(xin[(size_t)m * 768 + d]);
#pragma unroll
    for (int r = 0; r < 8; ++r) acc[r] += xv * As[r * 768 + d];
  }
#pragma unroll
  for (int r = 0; r < 8; ++r)
    for (int dd = 1; dd < 64; dd <<= 1) acc[r] += __shfl_xor(acc[r], dd);
  if (l == 0) {
#pragma unroll
    for (int r = 0; r < 8; ++r) low[m * 8 + r] = 2.0f * acc[r];
  }
}

// ---------------- 256x256 8-phase GEMM (T2+T3+T4+T5) ----------------
// C[M,N] = A[M,768] x B[N,768]^T ; MODE 0: qkv scatter epilogue; MODE 1: f32 out
// 8 waves (2Mx4N), wave-tile 128x64, BK=64 (2 k-slices of 32), 2 LDS slots x 64KB.
// LDS per slot: A [ks][256][32sh] at +0, B same at +32768. XOR swizzle:
// 16B-chunk' = chunk ^ ((row>>1)&3), applied on the GLOBAL source (linear LDS dest)
// and on ds_read addresses.
template <int MODE>
__global__ __launch_bounds__(512, 2) void k_gemm8(
    const unsigned short* __restrict__ A, const unsigned short* __restrict__ Bw,
    const float* __restrict__ bias, const float* __restrict__ low,
    const float* __restrict__ lorab, unsigned short* __restrict__ Qg,
    unsigned short* __restrict__ Kg, unsigned short* __restrict__ Vtg,
    float* __restrict__ outp, int M, int nbx) {
  __shared__ __align__(16) char lds[131072];
  const int tid = threadIdx.x;
  const int w = tid >> 6, l = tid & 63;
  const int lr = l & 15, lg = l >> 4;
  const int wm = w >> 2, wn = w & 3;
  // bijective XCD swizzle (m204)
  const int nwg = gridDim.x;
  const int orig = blockIdx.x;
  const int qq = nwg >> 3, rr = nwg & 7, xcd = orig & 7;
  const int wgid = (xcd < rr ? xcd * (qq + 1) : rr * (qq + 1) + (xcd - rr) * qq) + (orig >> 3);
  const int bx = wgid % nbx, by = wgid / nbx;
  const int m0 = by * 256, n0 = bx * 256;

  f32x4 acc[8][4];
#pragma unroll
  for (int i = 0; i < 8; ++i)
#pragma unroll
    for (int j = 0; j < 4; ++j) acc[i][j] = (f32x4){0.f, 0.f, 0.f, 0.f};

  auto* lds3 = (__attribute__((address_space(3))) char*)lds;
  const int swz = (lr >> 1) & 3;
  const int coff = ((lg ^ swz) << 4);  // swizzled 16B chunk byte offset
  const int ccg = (tid & 3) ^ ((tid >> 3) & 3);  // staging source chunk

  // stage one 16KB chunk (kind: 0=A,1=B), k-slice ks of K-tile t, into slot s.
  auto STAGE = [&](const unsigned short* __restrict__ src, int grbase, int grmax,
                   int s, int kind, int ks, int t) {
    const int ldsb = s * 65536 + kind * 32768 + ks * 16384 + w * 1024;
#pragma unroll
    for (int j = 0; j < 2; ++j) {
      int row = (tid >> 2) + j * 128;
      int grow = grbase + row;
      if (grow > grmax) grow = grmax;
      const unsigned short* g = src + (size_t)grow * 768 + t * 64 + ks * 32 + ccg * 8;
      __builtin_amdgcn_global_load_lds((const __attribute__((address_space(1))) void*)g,
                                       (__attribute__((address_space(3))) void*)(lds3 + ldsb + j * 8192),
                                       16, 0, 0);
    }
  };
  auto LDA = [&](int s, int ks, int mf) -> short8 {
    int row = wm * 128 + mf * 16 + lr;
    return *(const short8*)(lds + s * 65536 + ks * 16384 + row * 64 + coff);
  };
  auto LDB = [&](int s, int ks, int nf) -> short8 {
    int row = wn * 64 + nf * 16 + lr;
    return *(const short8*)(lds + s * 65536 + 32768 + ks * 16384 + row * 64 + coff);
  };

  const int NBMAX = (MODE == 0 ? 2303 : 767);
  const int Mc = M - 1;

  // prologue: stage tile 0's 4 chunks in consumption order
  STAGE(A, m0, Mc, 0, 0, 0, 0);
  STAGE(Bw, n0, NBMAX, 0, 1, 0, 0);
  STAGE(A, m0, Mc, 0, 0, 1, 0);
  STAGE(Bw, n0, NBMAX, 0, 1, 1, 0);

  short8 ar[4], br[4];

#define PH_PRE  SB; BAR; SB; __builtin_amdgcn_s_setprio(1)
#define PH_POST __builtin_amdgcn_s_setprio(0); SB

  for (int t = 0; t < 11; ++t) {
    const int s = t & 1, so = s ^ 1;
    // boundary checkpoint: tile t's A-k0/B-k0 landed; A-k1/B-k1 in flight
    asm volatile("s_waitcnt vmcnt(4)" ::: "memory");
    SB; BAR; SB;
    // P1
#pragma unroll
    for (int nf = 0; nf < 4; ++nf) br[nf] = LDB(s, 0, nf);
#pragma unroll
    for (int mf = 0; mf < 4; ++mf) ar[mf] = LDA(s, 0, mf);
    STAGE(A, m0, Mc, so, 0, 0, t + 1);
    PH_PRE;
#pragma unroll
    for (int mf = 0; mf < 4; ++mf)
#pragma unroll
      for (int nf = 0; nf < 4; ++nf)
        acc[mf][nf] = __builtin_amdgcn_mfma_f32_16x16x32_bf16(ar[mf], br[nf], acc[mf][nf], 0, 0, 0);
    PH_POST; BAR; SB;
    // P2
#pragma unroll
    for (int mf = 0; mf < 4; ++mf) ar[mf] = LDA(s, 0, mf + 4);
    STAGE(Bw, n0, NBMAX, so, 1, 0, t + 1);
    PH_PRE;
#pragma unroll
    for (int mf = 0; mf < 4; ++mf)
#pragma unroll
      for (int nf = 0; nf < 4; ++nf)
        acc[mf + 4][nf] = __builtin_amdgcn_mfma_f32_16x16x32_bf16(ar[mf], br[nf], acc[mf + 4][nf], 0, 0, 0);
    PH_POST;
    // mid checkpoint: tile t's A-k1/B-k1 landed; t+1's A-k0/B-k0 in flight
    asm volatile("s_waitcnt vmcnt(4)" ::: "memory");
    SB; BAR; SB;
    // P3
#pragma unroll
    for (int nf = 0; nf < 4; ++nf) br[nf] = LDB(s, 1, nf);
#pragma unroll
    for (int mf = 0; mf < 4; ++mf) ar[mf] = LDA(s, 1, mf);
    STAGE(A, m0, Mc, so, 0, 1, t + 1);
    PH_PRE;
#pragma unroll
    for (int mf = 0; mf < 4; ++mf)
#pragma unroll
      for (int nf = 0; nf < 4; ++nf)
        acc[mf][nf] = __builtin_amdgcn_mfma_f32_16x16x32_bf16(ar[mf], br[nf], acc[mf][nf], 0, 0, 0);
    PH_POST; BAR; SB;
    // P4
#pragma unroll
    for (int mf = 0; mf < 4; ++mf) ar[mf] = LDA(s, 1, mf + 4);
    STAGE(Bw, n0, NBMAX, so, 1, 1, t + 1);
    PH_PRE;
#pragma unroll
    for (int mf = 0; mf < 4; ++mf)
#pragma unroll
      for (int nf = 0; nf < 4; ++nf)
        acc[mf + 4][nf] = __builtin_amdgcn_mfma_f32_16x16x32_bf16(ar[mf], br[nf], acc[mf + 4][nf], 0, 0, 0);
    PH_POST;
  }
  // peeled last tile (t=11, slot 1): no staging
  {
    const int s = 1;
    asm volatile("s_waitcnt vmcnt(4)" ::: "memory");
    SB; BAR; SB;
#pragma unroll
    for (int nf = 0; nf < 4; ++nf) br[nf] = LDB(s, 0, nf);
#pragma unroll
    for (int mf = 0; mf < 4; ++mf) ar[mf] = LDA(s, 0, mf);
    PH_PRE;
#pragma unroll
    for (int mf = 0; mf < 4; ++mf)
#pragma unroll
      for (int nf = 0; nf < 4; ++nf)
        acc[mf][nf] = __builtin_amdgcn_mfma_f32_16x16x32_bf16(ar[mf], br[nf], acc[mf][nf], 0, 0, 0);
    PH_POST; BAR; SB;
#pragma unroll
    for (int mf = 0; mf < 4; ++mf) ar[mf] = LDA(s, 0, mf + 4);
    PH_PRE;
#pragma unroll
    for (int mf = 0; mf < 4; ++mf)
#pragma unroll
      for (int nf = 0; nf < 4; ++nf)
        acc[mf + 4][nf] = __builtin_amdgcn_mfma_f32_16x16x32_bf16(ar[mf], br[nf], acc[mf + 4][nf], 0, 0, 0);
    PH_POST;
    asm volatile("s_waitcnt vmcnt(0)" ::: "memory");
    SB; BAR; SB;
#pragma unroll
    for (int nf = 0; nf < 4; ++nf) br[nf] = LDB(s, 1, nf);
#pragma unroll
    for (int mf = 0; mf < 4; ++mf) ar[mf] = LDA(s, 1, mf);
    PH_PRE;
#pragma unroll
    for (int mf = 0; mf < 4; ++mf)
#pragma unroll
      for (int nf = 0; nf < 4; ++nf)
        acc[mf][nf] = __builtin_amdgcn_mfma_f32_16x16x32_bf16(ar[mf], br[nf], acc[mf][nf], 0, 0, 0);
    PH_POST; BAR; SB;
#pragma unroll
    for (int mf = 0; mf < 4; ++mf) ar[mf] = LDA(s, 1, mf + 4);
    PH_PRE;
#pragma unroll
    for (int mf = 0; mf < 4; ++mf)
#pragma unroll
      for (int nf = 0; nf < 4; ++nf)
        acc[mf + 4][nf] = __builtin_amdgcn_mfma_f32_16x16x32_bf16(ar[mf], br[nf], acc[mf + 4][nf], 0, 0, 0);
    PH_POST;
  }

  // epilogue: bias + rank-8 LoRA; MODE 0 scatter to Q/K/Vt bf16, MODE 1 f32 out
  float bo[4];
  float4 lb0[4], lb1[4];
  int which[4], hh[4], hd[4], ocol[4];
#pragma unroll
  for (int nf = 0; nf < 4; ++nf) {
    int o = n0 + wn * 64 + nf * 16 + lr;
    ocol[nf] = o;
    bo[nf] = bias[o];
    const float4* lb4 = (const float4*)(lorab + (size_t)o * 8);
    lb0[nf] = lb4[0];
    lb1[nf] = lb4[1];
    if (MODE == 0) {
      which[nf] = o / 768;
      int within = o - which[nf] * 768;
      hh[nf] = within >> 6;
      hd[nf] = within & 63;
    }
  }
#pragma unroll
  for (int mf = 0; mf < 8; ++mf) {
#pragma unroll
    for (int v = 0; v < 4; ++v) {
      int m = m0 + wm * 128 + mf * 16 + lg * 4 + v;
      if (m < M) {
        const float4* lp4 = (const float4*)(low + (size_t)m * 8);
        float4 l0 = lp4[0], l1 = lp4[1];
        int b = m / 197;
        int n = m - b * 197;
#pragma unroll
        for (int nf = 0; nf < 4; ++nf) {
          float val = acc[mf][nf][v] + bo[nf];
          val += l0.x * lb0[nf].x + l0.y * lb0[nf].y + l0.z * lb0[nf].z + l0.w * lb0[nf].w;
          val += l1.x * lb1[nf].x + l1.y * lb1[nf].y + l1.z * lb1[nf].z + l1.w * lb1[nf].w;
          if (MODE == 0) {
            int bh = b * 12 + hh[nf];
            unsigned short hv = f2bf(val);
            if (which[nf] == 0)      Qg[(bh * 224 + n) * 64 + hd[nf]] = hv;
            else if (which[nf] == 1) Kg[(bh * 224 + n) * 64 + hd[nf]] = hv;
            else                     Vtg[(bh * 64 + hd[nf]) * 224 + n] = hv;
          } else {
            outp[(size_t)m * 768 + ocol[nf]] = val;
          }
        }
      }
    }
  }
}

// ---------------- attention: one block per (b,h), full-row softmax ----------------
__global__ __launch_bounds__(256) void k_attn(const unsigned short* __restrict__ Qg,
                                              const unsigned short* __restrict__ Kg,
                                              const unsigned short* __restrict__ Vtg,
                                              unsigned short* __restrict__ aout) {
  __shared__ __align__(16) unsigned short Ps[4][16 * 224];
  const int bh = blockIdx.x;
  const int b = bh / 12, h = bh - b * 12;
  const unsigned short* Qb = Qg + (size_t)bh * (224 * 64);
  const unsigned short* Kb = Kg + (size_t)bh * (224 * 64);
  const unsigned short* Vb = Vtg + (size_t)bh * (64 * 224);
  const int w = threadIdx.x >> 6, l = threadIdx.x & 63;
  const int lr = l & 15, lg = l >> 4;
  for (int t = w; t < 13; t += 4) {
    const int q0 = t * 16;
    short8 aq0 = *(const short8*)(Qb + (q0 + lr) * 64 + lg * 8);
    short8 aq1 = *(const short8*)(Qb + (q0 + lr) * 64 + 32 + lg * 8);
    f32x4 s[14];
#pragma unroll
    for (int jt = 0; jt < 14; ++jt) {
      f32x4 a = (f32x4){0.f, 0.f, 0.f, 0.f};
      short8 bk0 = *(const short8*)(Kb + (jt * 16 + lr) * 64 + lg * 8);
      short8 bk1 = *(const short8*)(Kb + (jt * 16 + lr) * 64 + 32 + lg * 8);
      a = __builtin_amdgcn_mfma_f32_16x16x32_bf16(aq0, bk0, a, 0, 0, 0);
      a = __builtin_amdgcn_mfma_f32_16x16x32_bf16(aq1, bk1, a, 0, 0, 0);
      s[jt] = a;
    }
    float mx[4] = {-3.0e38f, -3.0e38f, -3.0e38f, -3.0e38f};
#pragma unroll
    for (int jt = 0; jt < 14; ++jt) {
      bool valid = (jt * 16 + lr) < 197;
#pragma unroll
      for (int v = 0; v < 4; ++v) {
        float sv = valid ? s[jt][v] : -1.0e30f;
        s[jt][v] = sv;
        mx[v] = fmaxf(mx[v], sv);
      }
    }
#pragma unroll
    for (int v = 0; v < 4; ++v) {
      mx[v] = fmaxf(mx[v], __shfl_xor(mx[v], 1));
      mx[v] = fmaxf(mx[v], __shfl_xor(mx[v], 2));
      mx[v] = fmaxf(mx[v], __shfl_xor(mx[v], 4));
      mx[v] = fmaxf(mx[v], __shfl_xor(mx[v], 8));
    }
    float sum[4] = {0.f, 0.f, 0.f, 0.f};
    const float cc = 0.125f * 1.44269504088896341f;
#pragma unroll
    for (int jt = 0; jt < 14; ++jt)
#pragma unroll
      for (int v = 0; v < 4; ++v) {
        float pv = exp2f((s[jt][v] - mx[v]) * cc);
        s[jt][v] = pv;
        sum[v] += pv;
      }
#pragma unroll
    for (int v = 0; v < 4; ++v) {
      sum[v] += __shfl_xor(sum[v], 1);
      sum[v] += __shfl_xor(sum[v], 2);
      sum[v] += __shfl_xor(sum[v], 4);
      sum[v] += __shfl_xor(sum[v], 8);
    }
    float inv[4];
#pragma unroll
    for (int v = 0; v < 4; ++v) inv[v] = 1.0f / sum[v];
    unsigned short* pw = &Ps[w][0];
#pragma unroll
    for (int jt = 0; jt < 14; ++jt)
#pragma unroll
      for (int v = 0; v < 4; ++v)
        pw[(lg * 4 + v) * 224 + jt * 16 + lr] = f2bf(s[jt][v] * inv[v]);
    f32x4 oacc[4];
#pragma unroll
    for (int jo = 0; jo < 4; ++jo) oacc[jo] = (f32x4){0.f, 0.f, 0.f, 0.f};
#pragma unroll
    for (int kk = 0; kk < 7; ++kk) {
      short8 pa = *(const short8*)(pw + lr * 224 + kk * 32 + lg * 8);
#pragma unroll
      for (int jo = 0; jo < 4; ++jo) {
        short8 bv = *(const short8*)(Vb + (jo * 16 + lr) * 224 + kk * 32 + lg * 8);
        oacc[jo] = __builtin_amdgcn_mfma_f32_16x16x32_bf16(pa, bv, oacc[jo], 0, 0, 0);
      }
    }
#pragma unroll
    for (int jo = 0; jo < 4; ++jo)
#pragma unroll
      for (int v = 0; v < 4; ++v) {
        int n = q0 + lg * 4 + v;
        if (n < 197) aout[((size_t)(b * 197 + n)) * 768 + h * 64 + jo * 16 + lr] = f2bf(oacc[jo][v]);
      }
  }
}

extern "C" void kernel_launch(void* const* d_in, const int* in_sizes, int n_in,
                              void* d_out, int out_size, void* d_ws, size_t ws_size,
                              hipStream_t stream) {
  const float* x      = (const float*)d_in[0];
  const float* qkv_w  = (const float*)d_in[1];
  const float* qkv_b  = (const float*)d_in[2];
  const float* qkv_la = (const float*)d_in[3];
  const float* qkv_lb = (const float*)d_in[4];
  const float* out_w  = (const float*)d_in[5];
  const float* out_b  = (const float*)d_in[6];
  const float* out_la = (const float*)d_in[7];
  const float* out_lb = (const float*)d_in[8];
  float* out = (float*)d_out;

  const int M = 64 * 197;  // 12608
  char* p = (char*)d_ws;
  auto carve = [&](size_t bytes) {
    char* r = p;
    p += (bytes + 255) & ~(size_t)255;
    return r;
  };
  unsigned short* xbf  = (unsigned short*)carve((size_t)M * 768 * 2);
  unsigned short* qwbf = (unsigned short*)carve((size_t)2304 * 768 * 2);
  unsigned short* owbf = (unsigned short*)carve((size_t)768 * 768 * 2);
  float* lowq          = (float*)carve((size_t)M * 8 * 4);
  float* lowo          = (float*)carve((size_t)M * 8 * 4);
  unsigned short* Qg   = (unsigned short*)carve((size_t)768 * 224 * 64 * 2);
  unsigned short* Kg   = (unsigned short*)carve((size_t)768 * 224 * 64 * 2);
  unsigned short* Vtg  = (unsigned short*)carve((size_t)768 * 64 * 224 * 2);
  unsigned short* aout = xbf;  // reuse: x_bf16 dead after qkv GEMM

  int n4q = 2304 * 768 / 4, n4o = 768 * 768 / 4;
  k_cvt<<<(n4q + 255) / 256, 256, 0, stream>>>(qkv_w, qwbf, n4q);
  k_cvt<<<(n4o + 255) / 256, 256, 0, stream>>>(out_w, owbf, n4o);
  k_zpad<<<(768 * 64 * 27 + 255) / 256, 256, 0, stream>>>(Vtg);
  k_lowcvt<<<(M + 3) / 4, 256, 0, stream>>>(x, qkv_la, xbf, lowq, M);
  k_gemm8<0><<<50 * 9, 512, 0, stream>>>(xbf, qwbf, qkv_b, lowq, qkv_lb, Qg, Kg, Vtg, nullptr, M, 9);
  k_attn<<<768, 256, 0, stream>>>(Qg, Kg, Vtg, aout);
  k_low<<<(M + 3) / 4, 256, 0, stream>>>(aout, out_la, lowo, M);
  k_gemm8<1><<<50 * 3, 512, 0, stream>>>(aout, owbf, out_b, lowo, out_lb, nullptr, nullptr, nullptr, out, M, 3);
}